// Round 1
// baseline (170.696 us; speedup 1.0000x reference)
//
#include <hip/hip_runtime.h>
#include <cstdint>
#include <cstddef>

#define BATCH 32
#define CH    256
#define NSP   4096          // 64*64 spatial
#define RED   64            // CH / 4
#define GAMMA 0.5f
#define NKT   (NSP / 64)    // K-steps of 64

typedef float f32x4 __attribute__((ext_vector_type(4)));
typedef short short8 __attribute__((ext_vector_type(8)));

__device__ inline unsigned short f2bf(float f) {
  uint32_t x = __float_as_uint(f);
  x += 0x7fffu + ((x >> 16) & 1u);           // round-to-nearest-even
  return (unsigned short)(x >> 16);
}
__device__ inline float bf2f(unsigned short u) {
  return __uint_as_float(((uint32_t)u) << 16);
}

// ---------------------------------------------------------------------------
// K1: per-batch Gram tile (128x128) via bf16 MFMA + fused exp/row-sum into
//     density[b][c] (atomicAdd). grid = 32 batches * 4 tiles.
// ---------------------------------------------------------------------------
__global__ __launch_bounds__(256, 1)
void gram_density_kernel(const float* __restrict__ x, float* __restrict__ density) {
  const int bx   = blockIdx.x;       // 0..127
  const int b    = bx >> 2;
  const int tr   = (bx >> 1) & 1;    // row tile (0/1)
  const int tc   = bx & 1;           // col tile (0/1)
  const int tid  = threadIdx.x;
  const int lane = tid & 63;
  const int wave = tid >> 6;
  const int wr   = wave >> 1;        // wave row quadrant (0/1)
  const int wc   = wave & 1;         // wave col quadrant (0/1)

  __shared__ unsigned short lA[128 * 64];    // 16 KiB, XOR-swizzled bf16
  __shared__ unsigned short lB[128 * 64];    // 16 KiB
  __shared__ float sqA[128];
  __shared__ float sqB[128];

  if (tid < 128) { sqA[tid] = 0.f; sqB[tid] = 0.f; }

  const int rsub = tid >> 4;   // 0..15  (sub-row within 16-row group)
  const int c4   = tid & 15;   // 0..15  (float4 column index; 64 floats/row)

  const float* baseA = x + (size_t)(b * CH + tr * 128) * NSP;
  const float* baseB = x + (size_t)(b * CH + tc * 128) * NSP;

  f32x4 pa[8], pb[8];
  float sqa_p[8], sqb_p[8];
#pragma unroll
  for (int i = 0; i < 8; ++i) { sqa_p[i] = 0.f; sqb_p[i] = 0.f; }

  // prologue: load K-tile 0 into registers
#pragma unroll
  for (int i = 0; i < 8; ++i) {
    int row = i * 16 + rsub;
    pa[i] = *reinterpret_cast<const f32x4*>(baseA + (size_t)row * NSP + c4 * 4);
    pb[i] = *reinterpret_cast<const f32x4*>(baseB + (size_t)row * NSP + c4 * 4);
  }

  f32x4 acc[4][4];
#pragma unroll
  for (int m = 0; m < 4; ++m)
#pragma unroll
    for (int n = 0; n < 4; ++n)
      acc[m][n] = (f32x4){0.f, 0.f, 0.f, 0.f};

  char* cA = (char*)lA;
  char* cB = (char*)lB;

  for (int kt = 0; kt < NKT; ++kt) {
    __syncthreads();   // previous iteration's frags fully read
    // ---- write staged registers (tile kt) to LDS, bf16, swizzled ----
#pragma unroll
    for (int i = 0; i < 8; ++i) {
      int row = i * 16 + rsub;
      int byte = row * 128 + c4 * 8;
      byte ^= (row & 7) << 4;

      unsigned short a0 = f2bf(pa[i][0]), a1 = f2bf(pa[i][1]),
                     a2 = f2bf(pa[i][2]), a3 = f2bf(pa[i][3]);
      float fa0 = bf2f(a0), fa1 = bf2f(a1), fa2 = bf2f(a2), fa3 = bf2f(a3);
      sqa_p[i] += fa0 * fa0 + fa1 * fa1 + fa2 * fa2 + fa3 * fa3;
      uint64_t wa = (uint64_t)a0 | ((uint64_t)a1 << 16) |
                    ((uint64_t)a2 << 32) | ((uint64_t)a3 << 48);
      *reinterpret_cast<uint64_t*>(cA + byte) = wa;

      unsigned short b0 = f2bf(pb[i][0]), b1v = f2bf(pb[i][1]),
                     b2v = f2bf(pb[i][2]), b3 = f2bf(pb[i][3]);
      float fb0 = bf2f(b0), fb1 = bf2f(b1v), fb2 = bf2f(b2v), fb3 = bf2f(b3);
      sqb_p[i] += fb0 * fb0 + fb1 * fb1 + fb2 * fb2 + fb3 * fb3;
      uint64_t wb = (uint64_t)b0 | ((uint64_t)b1v << 16) |
                    ((uint64_t)b2v << 32) | ((uint64_t)b3 << 48);
      *reinterpret_cast<uint64_t*>(cB + byte) = wb;
    }
    __syncthreads();

    // ---- prefetch next K-tile into registers (overlaps with MFMA below) ----
    if (kt + 1 < NKT) {
      const float* kA = baseA + (kt + 1) * 64;
      const float* kB = baseB + (kt + 1) * 64;
#pragma unroll
      for (int i = 0; i < 8; ++i) {
        int row = i * 16 + rsub;
        pa[i] = *reinterpret_cast<const f32x4*>(kA + (size_t)row * NSP + c4 * 4);
        pb[i] = *reinterpret_cast<const f32x4*>(kB + (size_t)row * NSP + c4 * 4);
      }
    }

    // ---- LDS -> fragments ----
    short8 af[4][2], bf[4][2];
#pragma unroll
    for (int m = 0; m < 4; ++m)
#pragma unroll
      for (int kh = 0; kh < 2; ++kh) {
        int rowa = wr * 64 + m * 16 + (lane & 15);
        int bytea = rowa * 128 + kh * 64 + ((lane >> 4) * 16);
        bytea ^= (rowa & 7) << 4;
        af[m][kh] = *reinterpret_cast<const short8*>(cA + bytea);

        int rowb = wc * 64 + m * 16 + (lane & 15);
        int byteb = rowb * 128 + kh * 64 + ((lane >> 4) * 16);
        byteb ^= (rowb & 7) << 4;
        bf[m][kh] = *reinterpret_cast<const short8*>(cB + byteb);
      }

    // ---- MFMA ----
#pragma unroll
    for (int m = 0; m < 4; ++m)
#pragma unroll
      for (int n = 0; n < 4; ++n)
#pragma unroll
        for (int kh = 0; kh < 2; ++kh)
          acc[m][n] = __builtin_amdgcn_mfma_f32_16x16x32_bf16(
              af[m][kh], bf[n][kh], acc[m][n], 0, 0, 0);
  }

  // ---- reduce per-thread sq partials into LDS ----
#pragma unroll
  for (int i = 0; i < 8; ++i) {
    int row = i * 16 + rsub;
    atomicAdd(&sqA[row], sqa_p[i]);
    atomicAdd(&sqB[row], sqb_p[i]);
  }
  __syncthreads();

  // ---- epilogue: d2 -> exp -> row-sum -> density atomics ----
  // C/D layout (16x16x32): col = lane&15, row = (lane>>4)*4 + reg
#pragma unroll
  for (int m = 0; m < 4; ++m) {
#pragma unroll
    for (int r = 0; r < 4; ++r) {
      int rowL = wr * 64 + m * 16 + ((lane >> 4) * 4 + r);
      float sqr = sqA[rowL];
      float s = 0.f;
#pragma unroll
      for (int n = 0; n < 4; ++n) {
        int colL = wc * 64 + n * 16 + (lane & 15);
        float g = acc[m][n][r];
        float d2 = sqr + sqB[colL] - 2.f * g;
        d2 = fmaxf(d2, 0.f);
        s += __expf(-0.5f * d2);
      }
      s += __shfl_xor(s, 1);
      s += __shfl_xor(s, 2);
      s += __shfl_xor(s, 4);
      s += __shfl_xor(s, 8);
      if ((lane & 15) == 0) {
        atomicAdd(&density[b * CH + tr * 128 + rowL], s * (1.0f / CH));
      }
    }
  }
}

// ---------------------------------------------------------------------------
// K2: per-batch MLP  scale = sigmoid(relu(density@W1+b1)@W2+b2) + GAMMA
// ---------------------------------------------------------------------------
__global__ __launch_bounds__(256)
void mlp_kernel(const float* __restrict__ density,
                const float* __restrict__ w1, const float* __restrict__ b1,
                const float* __restrict__ w2, const float* __restrict__ b2,
                float* __restrict__ scale) {
  const int b = blockIdx.x;
  const int t = threadIdx.x;
  __shared__ float dens[CH];
  __shared__ float hid[RED];
  dens[t] = density[b * CH + t];
  __syncthreads();
  if (t < RED) {
    float s = b1[t];
    for (int c = 0; c < CH; ++c) s += dens[c] * w1[c * RED + t];
    hid[t] = fmaxf(s, 0.f);
  }
  __syncthreads();
  float s = b2[t];
#pragma unroll
  for (int h = 0; h < RED; ++h) s += hid[h] * w2[h * CH + t];
  scale[b * CH + t] = 1.f / (1.f + __expf(-s)) + GAMMA;
}

// ---------------------------------------------------------------------------
// K3: out = x * scale[b,c]   (float4 grid-stride)
// ---------------------------------------------------------------------------
__global__ __launch_bounds__(256)
void scale_kernel(const f32x4* __restrict__ x, const float* __restrict__ scale,
                  f32x4* __restrict__ out, int n4) {
  const int stride = gridDim.x * blockDim.x;
  for (int i = blockIdx.x * blockDim.x + threadIdx.x; i < n4; i += stride) {
    float s = scale[i >> 10];          // 1024 float4 per (b,c) row
    out[i] = x[i] * s;
  }
}

extern "C" void kernel_launch(void* const* d_in, const int* in_sizes, int n_in,
                              void* d_out, int out_size, void* d_ws, size_t ws_size,
                              hipStream_t stream) {
  const float* x  = (const float*)d_in[0];
  const float* w1 = (const float*)d_in[1];
  const float* b1 = (const float*)d_in[2];
  const float* w2 = (const float*)d_in[3];
  const float* b2 = (const float*)d_in[4];
  float* out = (float*)d_out;

  float* density = (float*)d_ws;                 // 32*256 floats
  float* scale   = density + BATCH * CH;         // 32*256 floats

  hipMemsetAsync(density, 0, BATCH * CH * sizeof(float), stream);

  gram_density_kernel<<<dim3(BATCH * 4), dim3(256), 0, stream>>>(x, density);
  mlp_kernel<<<dim3(BATCH), dim3(256), 0, stream>>>(density, w1, b1, w2, b2, scale);

  const int n4 = BATCH * CH * NSP / 4;
  scale_kernel<<<dim3(2048), dim3(256), 0, stream>>>(
      (const f32x4*)x, scale, (f32x4*)out, n4);
}

// Round 2
// 132.759 us; speedup vs baseline: 1.2858x; 1.2858x over previous
//
#include <hip/hip_runtime.h>
#include <hip/hip_bf16.h>
#include <cstdint>
#include <cstddef>

#define BATCH 32
#define CH    256
#define NSP   4096          // 64*64 spatial
#define RED   64            // CH / 4
#define GAMMA 0.5f
#define NSPLIT 2            // split-K factor
#define KSEG  (NSP / NSPLIT)      // 2048
#define NKT   (KSEG / 64)         // 32 K-iters of 64
#define TILE_ELEMS (128 * 128)
#define SLICE_STRIDE ((size_t)BATCH * 4 * TILE_ELEMS)   // elems per split slice

typedef float f32x4 __attribute__((ext_vector_type(4)));
typedef short short8 __attribute__((ext_vector_type(8)));

static __device__ inline unsigned short bfu(float f) {
  __hip_bfloat16 h = __float2bfloat16(f);   // RNE; compiler emits v_cvt_pk_bf16_f32
  return __builtin_bit_cast(unsigned short, h);
}

// ---------------------------------------------------------------------------
// K1: split-K partial Gram. grid = 32 b * 4 tiles * 2 splits = 256 blocks,
//     512 threads (8 waves, 2x4), 128x128 tile, BK=64, bf16 MFMA.
//     gpart[s][b][tile][128][128] (f32)
// ---------------------------------------------------------------------------
__global__ __launch_bounds__(512, 1)
void gram_partial_kernel(const float* __restrict__ x, float* __restrict__ gpart) {
  const int bx   = blockIdx.x;       // 0..255
  const int s    = bx & 1;
  const int tile = (bx >> 1) & 3;
  const int b    = bx >> 3;
  const int tr   = tile >> 1;
  const int tc   = tile & 1;
  const int tid  = threadIdx.x;
  const int lane = tid & 63;
  const int wave = tid >> 6;
  const int wr   = wave >> 2;        // 0..1  (64-row half)
  const int wc   = wave & 3;         // 0..3  (32-col quarter)

  __shared__ unsigned short lA[128 * 64];    // 16 KiB, XOR-swizzled bf16
  __shared__ unsigned short lB[128 * 64];    // 16 KiB

  const int rsub = tid >> 4;   // 0..31 (row within 32-row group)
  const int c4   = tid & 15;   // float4 column index (64 floats per K-slab row)

  const float* baseA = x + (size_t)(b * CH + tr * 128) * NSP + s * KSEG;
  const float* baseB = x + (size_t)(b * CH + tc * 128) * NSP + s * KSEG;

  f32x4 pa[4], pb[4];
  // prologue: K-tile 0 into registers
#pragma unroll
  for (int i = 0; i < 4; ++i) {
    int row = i * 32 + rsub;
    pa[i] = *reinterpret_cast<const f32x4*>(baseA + (size_t)row * NSP + c4 * 4);
    pb[i] = *reinterpret_cast<const f32x4*>(baseB + (size_t)row * NSP + c4 * 4);
  }

  f32x4 acc[4][2];
#pragma unroll
  for (int m = 0; m < 4; ++m)
#pragma unroll
    for (int n = 0; n < 2; ++n)
      acc[m][n] = (f32x4){0.f, 0.f, 0.f, 0.f};

  char* cA = (char*)lA;
  char* cB = (char*)lB;

  for (int kt = 0; kt < NKT; ++kt) {
    __syncthreads();   // previous iteration's frags fully consumed
    // ---- convert staged registers to bf16 and write to LDS (swizzled) ----
#pragma unroll
    for (int i = 0; i < 4; ++i) {
      int row = i * 32 + rsub;
      int byte = row * 128 + c4 * 8;
      byte ^= (row & 7) << 4;

      uint64_t wa = (uint64_t)bfu(pa[i][0]) | ((uint64_t)bfu(pa[i][1]) << 16) |
                    ((uint64_t)bfu(pa[i][2]) << 32) | ((uint64_t)bfu(pa[i][3]) << 48);
      *reinterpret_cast<uint64_t*>(cA + byte) = wa;

      uint64_t wb = (uint64_t)bfu(pb[i][0]) | ((uint64_t)bfu(pb[i][1]) << 16) |
                    ((uint64_t)bfu(pb[i][2]) << 32) | ((uint64_t)bfu(pb[i][3]) << 48);
      *reinterpret_cast<uint64_t*>(cB + byte) = wb;
    }
    __syncthreads();

    // ---- prefetch next K-slab into registers (overlaps MFMA below) ----
    if (kt + 1 < NKT) {
      const float* kA = baseA + (kt + 1) * 64;
      const float* kB = baseB + (kt + 1) * 64;
#pragma unroll
      for (int i = 0; i < 4; ++i) {
        int row = i * 32 + rsub;
        pa[i] = *reinterpret_cast<const f32x4*>(kA + (size_t)row * NSP + c4 * 4);
        pb[i] = *reinterpret_cast<const f32x4*>(kB + (size_t)row * NSP + c4 * 4);
      }
    }

    // ---- LDS -> fragments ----
    short8 af[4][2], bff[2][2];
#pragma unroll
    for (int m = 0; m < 4; ++m)
#pragma unroll
      for (int kh = 0; kh < 2; ++kh) {
        int rowa = wr * 64 + m * 16 + (lane & 15);
        int bytea = rowa * 128 + kh * 64 + ((lane >> 4) * 16);
        bytea ^= (rowa & 7) << 4;
        af[m][kh] = *reinterpret_cast<const short8*>(cA + bytea);
      }
#pragma unroll
    for (int n = 0; n < 2; ++n)
#pragma unroll
      for (int kh = 0; kh < 2; ++kh) {
        int rowb = wc * 32 + n * 16 + (lane & 15);
        int byteb = rowb * 128 + kh * 64 + ((lane >> 4) * 16);
        byteb ^= (rowb & 7) << 4;
        bff[n][kh] = *reinterpret_cast<const short8*>(cB + byteb);
      }

    // ---- MFMA ----
#pragma unroll
    for (int m = 0; m < 4; ++m)
#pragma unroll
      for (int n = 0; n < 2; ++n)
#pragma unroll
        for (int kh = 0; kh < 2; ++kh)
          acc[m][n] = __builtin_amdgcn_mfma_f32_16x16x32_bf16(
              af[m][kh], bff[n][kh], acc[m][n], 0, 0, 0);
  }

  // ---- store partial tile ----
  float* g = gpart + ((size_t)s * BATCH + b) * 4 * TILE_ELEMS + (size_t)tile * TILE_ELEMS;
#pragma unroll
  for (int m = 0; m < 4; ++m)
#pragma unroll
    for (int n = 0; n < 2; ++n)
#pragma unroll
      for (int r = 0; r < 4; ++r) {
        int row = wr * 64 + m * 16 + ((lane >> 4) * 4 + r);
        int col = wc * 32 + n * 16 + (lane & 15);
        g[row * 128 + col] = acc[m][n][r];
      }
}

// ---------------------------------------------------------------------------
// K2: density[b][r] = (1/CH) * sum_j exp(-0.5*max(sq r + sq j - 2 g, 0))
//     sq taken from the Gram diagonal (exact cancellation on the diagonal).
//     grid = 32 b * 4 row-quarters = 128 blocks, 256 threads; one wave per row.
// ---------------------------------------------------------------------------
__global__ __launch_bounds__(256)
void density_kernel(const float* __restrict__ gpart, float* __restrict__ density) {
  const int blk  = blockIdx.x;   // 0..127
  const int b    = blk >> 2;
  const int rq   = blk & 3;
  const int t    = threadIdx.x;
  const int lane = t & 63;
  const int wave = t >> 6;

  __shared__ float sq[CH];
  {
    int jt = t >> 7, jr = t & 127;
    size_t off = ((size_t)b * 4 + (size_t)jt * 3) * TILE_ELEMS + (size_t)jr * 128 + jr;
    sq[t] = gpart[off] + gpart[off + SLICE_STRIDE];
  }
  __syncthreads();

  const float* gb = gpart + (size_t)b * 4 * TILE_ELEMS;
#pragma unroll 1
  for (int rr = 0; rr < 16; ++rr) {
    int r = rq * 64 + wave * 16 + rr;
    int rt = r >> 7, rrow = r & 127;
    float sqr = sq[r];
    float ssum = 0.f;
#pragma unroll
    for (int cc = 0; cc < 4; ++cc) {
      int j = cc * 64 + lane;
      int jt = j >> 7;
      size_t off = (size_t)(rt * 2 + jt) * TILE_ELEMS + (size_t)rrow * 128 + (j & 127);
      float g = gb[off] + gb[off + SLICE_STRIDE];
      float d2 = fmaxf(sqr + sq[j] - 2.f * g, 0.f);
      ssum += __expf(-0.5f * d2);
    }
    ssum += __shfl_xor(ssum, 1);
    ssum += __shfl_xor(ssum, 2);
    ssum += __shfl_xor(ssum, 4);
    ssum += __shfl_xor(ssum, 8);
    ssum += __shfl_xor(ssum, 16);
    ssum += __shfl_xor(ssum, 32);
    if (lane == 0) density[b * CH + r] = ssum * (1.0f / CH);
  }
}

// ---------------------------------------------------------------------------
// K3: per-batch MLP  scale = sigmoid(relu(density@W1+b1)@W2+b2) + GAMMA
// ---------------------------------------------------------------------------
__global__ __launch_bounds__(256)
void mlp_kernel(const float* __restrict__ density,
                const float* __restrict__ w1, const float* __restrict__ b1,
                const float* __restrict__ w2, const float* __restrict__ b2,
                float* __restrict__ scale) {
  const int b = blockIdx.x;
  const int t = threadIdx.x;
  __shared__ float dens[CH];
  __shared__ float hid[RED];
  dens[t] = density[b * CH + t];
  __syncthreads();
  if (t < RED) {
    float s = b1[t];
    for (int c = 0; c < CH; ++c) s += dens[c] * w1[c * RED + t];
    hid[t] = fmaxf(s, 0.f);
  }
  __syncthreads();
  float s = b2[t];
#pragma unroll
  for (int h = 0; h < RED; ++h) s += hid[h] * w2[h * CH + t];
  scale[b * CH + t] = 1.f / (1.f + __expf(-s)) + GAMMA;
}

// ---------------------------------------------------------------------------
// K4: out = x * scale[b,c]   (float4 grid-stride)
// ---------------------------------------------------------------------------
__global__ __launch_bounds__(256)
void scale_kernel(const f32x4* __restrict__ x, const float* __restrict__ scale,
                  f32x4* __restrict__ out, int n4) {
  const int stride = gridDim.x * blockDim.x;
  for (int i = blockIdx.x * blockDim.x + threadIdx.x; i < n4; i += stride) {
    float s = scale[i >> 10];          // 1024 float4 per (b,c) row
    out[i] = x[i] * s;
  }
}

extern "C" void kernel_launch(void* const* d_in, const int* in_sizes, int n_in,
                              void* d_out, int out_size, void* d_ws, size_t ws_size,
                              hipStream_t stream) {
  const float* x  = (const float*)d_in[0];
  const float* w1 = (const float*)d_in[1];
  const float* b1 = (const float*)d_in[2];
  const float* w2 = (const float*)d_in[3];
  const float* b2 = (const float*)d_in[4];
  float* out = (float*)d_out;

  float* gpart   = (float*)d_ws;                          // 2*32*4*16384 f32 = 16.8 MB
  float* density = gpart + NSPLIT * SLICE_STRIDE;         // 32*256
  float* scale   = density + BATCH * CH;                  // 32*256

  gram_partial_kernel<<<dim3(BATCH * 4 * NSPLIT), dim3(512), 0, stream>>>(x, gpart);
  density_kernel<<<dim3(BATCH * 4), dim3(256), 0, stream>>>(gpart, density);
  mlp_kernel<<<dim3(BATCH), dim3(256), 0, stream>>>(density, w1, b1, w2, b2, scale);

  const int n4 = BATCH * CH * NSP / 4;
  scale_kernel<<<dim3(2048), dim3(256), 0, stream>>>(
      (const f32x4*)x, scale, (f32x4*)out, n4);
}